// Round 5
// baseline (4259.491 us; speedup 1.0000x reference)
//
#include <hip/hip_runtime.h>
#include <hip/hip_bf16.h>
#include <cstdint>

#define TT 128
#define BB 64
#define II 1024
#define HD 4096
#define N_IH 262144
#define N_HH 1048576
#define LN_EPS 1e-5f
#define NREP 16
#define NB_HH 32768   // 8 col-tiles * 4096 rows
#define NB_IH 8192    // 2 col-tiles * 4096 rows

typedef unsigned int u32;
typedef unsigned short u16;

__device__ __forceinline__ u32 f2bf_bits(float f) {
  u32 u = __float_as_uint(f);
  return (u + 0x7FFFu + ((u >> 16) & 1u)) >> 16;   // RTNE, finite inputs
}

// ---------------- preprocessing ----------------
// buckets keyed by (col_tile, row): b = (c>>9)*4096 + r  -> per-(block,tile)
// meta spans are contiguous in memory (r-consecutive for fixed tile).

__global__ void k_hist2(const int* __restrict__ rows, const int* __restrict__ cols,
                        int n, int* __restrict__ hist) {
  int e = blockIdx.x * 256 + threadIdx.x;
  if (e < n) {
    int b = (cols[e] >> 9) * HD + rows[e];
    atomicAdd(&hist[b * 64 + (blockIdx.x & 63)], 1);
  }
}

// wave per bucket: padded (to 4) bucket total
__global__ __launch_bounds__(256) void k_rowtot2(const int* __restrict__ hist, int* __restrict__ rowtot) {
  int w = threadIdx.x >> 6, lane = threadIdx.x & 63;
  int b = blockIdx.x * 4 + w;
  int c = hist[b * 64 + lane];
#pragma unroll
  for (int d = 1; d < 64; d <<= 1) c += __shfl_xor(c, d);
  if (lane == 0) rowtot[b] = (c + 3) & ~3;
}

// one block, 256 threads: exclusive scan of NB=256*npt padded bucket totals
__global__ void k_scan3(const int* __restrict__ rowtot, int* __restrict__ rp, int npt) {
  __shared__ int ps[256];
  int t = threadIdx.x;
  int base = t * npt;
  int tot = 0;
  for (int j = 0; j < npt; ++j) tot += rowtot[base + j];
  ps[t] = tot;
  __syncthreads();
  for (int d = 1; d < 256; d <<= 1) {
    int v = (t >= d) ? ps[t - d] : 0;
    __syncthreads();
    if (t >= d) ps[t] += v;
    __syncthreads();
  }
  int run = ps[t] - tot;   // exclusive prefix
  for (int j = 0; j < npt; ++j) { rp[base + j] = run; run += rowtot[base + j]; }
  if (t == 255) rp[256 * npt] = run;
}

// wave per bucket: cur[b*64+rep] = rp[b] + exclusive_scan(hist[b][*])
__global__ __launch_bounds__(256) void k_repbase2(const int* __restrict__ hist, const int* __restrict__ rp,
                                                  int* __restrict__ cur) {
  int w = threadIdx.x >> 6, lane = threadIdx.x & 63;
  int b = blockIdx.x * 4 + w;
  int c = hist[b * 64 + lane];
  int x = c;
#pragma unroll
  for (int d = 1; d < 64; d <<= 1) {
    int y = __shfl_up(x, d, 64);
    if (lane >= d) x += y;
  }
  cur[b * 64 + lane] = rp[b] + (x - c);
}

__global__ void k_scatter2(const int* __restrict__ rows, const int* __restrict__ cols,
                           const float* __restrict__ vals, int n,
                           int* __restrict__ cur, u32* __restrict__ meta,
                           const float* __restrict__ gamma, const float* __restrict__ beta,
                           float* __restrict__ rvg_rep, float* __restrict__ rvb_rep, int fold) {
  int e = blockIdx.x * 256 + threadIdx.x;
  if (e >= n) return;
  int rep = blockIdx.x & 63;
  int r = rows[e], c = cols[e];
  float v = vals[e];
  float vg = v;
  if (fold) {
    vg = v * gamma[c];
    atomicAdd(&rvg_rep[r * 64 + rep], vg);
    atomicAdd(&rvb_rep[r * 64 + rep], v * beta[c]);
  }
  int b = (c >> 9) * HD + r;
  u32 word = (f2bf_bits(vg) << 16) | (u32)(c & 511);
  int pos = atomicAdd(&cur[b * 64 + rep], 1);
  meta[pos] = word;
}

// wave per row: reduce 64 replicas -> rowvg/rowvb
__global__ __launch_bounds__(256) void k_rvred(const float* __restrict__ rvg_rep,
                                               const float* __restrict__ rvb_rep,
                                               float* __restrict__ rowvg, float* __restrict__ rowvb) {
  int w = threadIdx.x >> 6, lane = threadIdx.x & 63;
  int row = blockIdx.x * 4 + w;
  float a = rvg_rep[row * 64 + lane];
  float b = rvb_rep[row * 64 + lane];
#pragma unroll
  for (int d = 1; d < 64; d <<= 1) { a += __shfl_xor(a, d); b += __shfl_xor(b, d); }
  if (lane == 0) { rowvg[row] = a; rowvb[row] = b; }
}

// x (B,T,I) fp32 -> xt (T,I,B) bf16
__global__ __launch_bounds__(256) void k_xt(const float* __restrict__ x, u16* __restrict__ xt) {
  __shared__ u16 tile[64][66];
  int t = blockIdx.x >> 4, i0 = (blockIdx.x & 15) << 6;
  int w = threadIdx.x >> 6, lane = threadIdx.x & 63;
#pragma unroll
  for (int k = 0; k < 16; ++k) {
    int b = w * 16 + k;
    float v = x[((size_t)b * TT + t) * II + i0 + lane];
    tile[b][lane] = (u16)f2bf_bits(v);
  }
  __syncthreads();
#pragma unroll
  for (int k = 0; k < 16; ++k) {
    int i = w * 16 + k;
    xt[((size_t)t * II + i0 + i) * BB + lane] = tile[lane][i];
  }
}

// ---------------- per-step kernel: col-tiled streaming SpMM ----------------
// grid 256 (1 block/CU), 256 thr. Block owns 16 rows; thread (r_loc=tid>>4,
// bi=tid&15) accumulates its row's 4-batch slice. 10 col-tiles (8 HH + 2 IH):
// activation tile (512 cols x 64b bf16 = 64KB) + its meta span reg-staged
// coalesced into double-buffered LDS; tile k+1 loads issue before processing
// tile k (pure LDS) -> HBM/L2 latency hidden, all global traffic coalesced.

__device__ __forceinline__ void t_load(uint4 ga[16], uint4& gm, const char* asrc,
                                       const u32* msrc, int w, int lane) {
  const char* s = asrc + (size_t)(w * 16384 + lane * 16);
#pragma unroll
  for (int i = 0; i < 16; ++i) ga[i] = *(const uint4*)(s + i * 1024);
  if (w < 3) gm = *(const uint4*)(msrc + w * 256 + lane * 4);
}

__device__ __forceinline__ void t_write(const uint4 ga[16], const uint4& gm,
                                        u32* abuf, u32* mbuf, int w, int lane) {
  char* d = (char*)abuf + (w * 16384 + lane * 16);
#pragma unroll
  for (int i = 0; i < 16; ++i) *(uint4*)(d + i * 1024) = ga[i];
  if (w < 3) *(uint4*)(mbuf + w * 256 + lane * 4) = gm;
}

__device__ __forceinline__ void t_proc(const u32* abuf, const u32* mbuf,
                                       int o, int n, int bs2, float acc[4]) {
  const u32* mp = mbuf + o;
  for (int e = 0; e < n; e += 4) {
    uint4 m4 = *(const uint4*)(mp + e);
    u32 mm[4] = {m4.x, m4.y, m4.z, m4.w};
#pragma unroll
    for (int j = 0; j < 4; ++j) {
      u32 m = mm[j];
      float v = __uint_as_float(m & 0xFFFF0000u);
      const char* ap = (const char*)abuf + (m & 511u) * 128u + bs2;
      uint2 d = *(const uint2*)ap;
      acc[0] += v * __uint_as_float(d.x << 16);
      acc[1] += v * __uint_as_float(d.x & 0xFFFF0000u);
      acc[2] += v * __uint_as_float(d.y << 16);
      acc[3] += v * __uint_as_float(d.y & 0xFFFF0000u);
    }
  }
}

__global__ __launch_bounds__(256, 1) void k_step2(
    const u32* __restrict__ meta_hh, const int* __restrict__ rp_hh,
    const u32* __restrict__ meta_ih, const int* __restrict__ rp_ih,
    const u16* __restrict__ xt_t, const u16* __restrict__ Aprev,
    u16* __restrict__ Acur,
    const float* __restrict__ st_prev, float* __restrict__ st_cur,
    const float* __restrict__ b_ih, const float* __restrict__ b_hh,
    const float* __restrict__ rowvg, const float* __restrict__ rowvb, int first) {
  __shared__ __align__(16) u32 AT[2][16384];   // 2 x 64KB activation tiles
  __shared__ __align__(16) u32 MT[2][768];     // 2 x 3KB meta spans
  __shared__ float s_mu[64], s_rs[64], s_sum[64], s_sq[64];
  int tid = threadIdx.x, w = tid >> 6, lane = tid & 63;
  int r_loc = tid >> 4, bi = tid & 15;
  int r0 = blockIdx.x * 16;
  int r = r0 + r_loc;
  int bs2 = bi * 8;              // byte offset of this thread's 4-bf16 batch slice

  if (tid < 64) { s_sum[tid] = 0.f; s_sq[tid] = 0.f; }
  if (w == 3 && !first) {
    float s = 0.f, q = 0.f;
#pragma unroll
    for (int r2 = 0; r2 < NREP; ++r2) {
      s += st_prev[r2 * 64 + lane];
      q += st_prev[NREP * 64 + r2 * 64 + lane];
    }
    float mu = s * (1.0f / HD);
    float var = q * (1.0f / HD) - mu * mu;
    s_mu[lane] = mu;
    s_rs[lane] = rsqrtf(var + LN_EPS);
  }

  // per-tile geometry (all mult of 4 -> aligned uint4 meta reads)
  int sp[10], off[10], nn[10];
#pragma unroll
  for (int k = 0; k < 10; ++k) {
    int ct = (k < 8) ? k : (k - 8);
    const int* rp = (k < 8) ? rp_hh : rp_ih;
    int b0 = ct * HD + r0;
    int bk = ct * HD + r;
    int v0 = rp[b0];
    int s = rp[bk];
    int en = rp[bk + 1];
    sp[k] = v0; off[k] = s - v0; nn[k] = en - s;
  }
  float bihv = b_ih[r], bhhv = b_hh[r];
  float rvg_r = rowvg[r];
  float bsum = bihv + bhhv + (first ? 0.f : rowvb[r]);

  float accH[4] = {0, 0, 0, 0}, accI[4] = {0, 0, 0, 0};
  uint4 ga[16]; uint4 gm;

  if (!first) {
    t_load(ga, gm, (const char*)Aprev, meta_hh + sp[0], w, lane);
    t_write(ga, gm, AT[0], MT[0], w, lane);
    __syncthreads();
#pragma unroll
    for (int k = 0; k < 10; ++k) {
      int cb = k & 1;
      if (k < 9) {
        const char* asrc = (k + 1 < 8) ? (const char*)Aprev + (size_t)(k + 1) * 65536
                                       : (const char*)xt_t + (size_t)(k + 1 - 8) * 65536;
        const u32* msrc = ((k + 1 < 8) ? meta_hh : meta_ih) + sp[k + 1];
        t_load(ga, gm, asrc, msrc, w, lane);
      }
      t_proc(AT[cb], MT[cb], off[k], nn[k], bs2, (k < 8) ? accH : accI);
      if (k < 9) t_write(ga, gm, AT[cb ^ 1], MT[cb ^ 1], w, lane);
      __syncthreads();
    }
  } else {
    t_load(ga, gm, (const char*)xt_t, meta_ih + sp[8], w, lane);
    t_write(ga, gm, AT[0], MT[0], w, lane);
    __syncthreads();
    t_load(ga, gm, (const char*)xt_t + 65536, meta_ih + sp[9], w, lane);
    t_proc(AT[0], MT[0], off[8], nn[8], bs2, accI);
    t_write(ga, gm, AT[1], MT[1], w, lane);
    __syncthreads();
    t_proc(AT[1], MT[1], off[9], nn[9], bs2, accI);
  }

  // epilogue
  float h4[4];
#pragma unroll
  for (int j = 0; j < 4; ++j) {
    int b = bi * 4 + j;
    float pre = accI[j] + bsum;
    if (!first) pre += s_rs[b] * (accH[j] - s_mu[b] * rvg_r);
    h4[j] = 1.0f - 2.0f / (__expf(2.0f * pre) + 1.0f);   // tanh
  }
  u32 p0 = f2bf_bits(h4[0]) | (f2bf_bits(h4[1]) << 16);
  u32 p1 = f2bf_bits(h4[2]) | (f2bf_bits(h4[3]) << 16);
  uint2 pk; pk.x = p0; pk.y = p1;
  *(uint2*)((char*)Acur + (size_t)r * 128 + bs2) = pk;
#pragma unroll
  for (int j = 0; j < 4; ++j) {
    int b = bi * 4 + j;
    atomicAdd(&s_sum[b], h4[j]);
    atomicAdd(&s_sq[b], h4[j] * h4[j]);
  }
  __syncthreads();
  if (tid < 64) {
    int rep = blockIdx.x & (NREP - 1);
    atomicAdd(&st_cur[rep * 64 + tid], s_sum[tid]);
    atomicAdd(&st_cur[NREP * 64 + rep * 64 + tid], s_sq[tid]);
  }
}

// ---------------- final output ----------------

__global__ __launch_bounds__(256) void k_out(const u16* __restrict__ A,
                                             const float* __restrict__ stats,
                                             const float* __restrict__ gamma,
                                             const float* __restrict__ beta,
                                             float* __restrict__ out) {
  __shared__ float s_mu[64], s_rs[64];
  __shared__ float tile[64][65];
  int t = blockIdx.x >> 6, r0 = (blockIdx.x & 63) << 6;
  int tid = threadIdx.x, w = tid >> 6, lane = tid & 63;
  const float* st = stats + (size_t)t * (2 * NREP * 64);
  if (tid < 64) {
    float s = 0.f, q = 0.f;
#pragma unroll
    for (int r2 = 0; r2 < NREP; ++r2) {
      s += st[r2 * 64 + tid];
      q += st[NREP * 64 + r2 * 64 + tid];
    }
    float mu = s * (1.0f / HD);
    float var = q * (1.0f / HD) - mu * mu;
    s_mu[tid] = mu;
    s_rs[tid] = rsqrtf(var + LN_EPS);
  }
  __syncthreads();
#pragma unroll
  for (int k = 0; k < 16; ++k) {
    int r = r0 + w * 16 + k;
    float a = __uint_as_float(((u32)A[((size_t)t * HD + r) * BB + lane]) << 16);
    float hn = (a - s_mu[lane]) * s_rs[lane] * gamma[r] + beta[r];
    tile[w * 16 + k][lane] = hn;
  }
  __syncthreads();
#pragma unroll
  for (int k = 0; k < 16; ++k) {
    int b = w * 16 + k;
    float v = tile[lane][b];
    out[((size_t)b * TT + t) * HD + r0 + lane] = v;
    if (t == TT - 1) out[(size_t)BB * TT * HD + (size_t)b * HD + r0 + lane] = v;
  }
}

// ---------------- host launch ----------------

extern "C" void kernel_launch(void* const* d_in, const int* in_sizes, int n_in,
                              void* d_out, int out_size, void* d_ws, size_t ws_size,
                              hipStream_t stream) {
  const float* x = (const float*)d_in[0];
  const int* ih_rows = (const int*)d_in[1];
  const int* ih_cols = (const int*)d_in[2];
  const float* ih_vals = (const float*)d_in[3];
  const int* hh_rows = (const int*)d_in[4];
  const int* hh_cols = (const int*)d_in[5];
  const float* hh_vals = (const float*)d_in[6];
  const float* b_ih = (const float*)d_in[7];
  const float* b_hh = (const float*)d_in[8];
  const float* gamma = (const float*)d_in[9];
  const float* beta = (const float*)d_in[10];

  char* ws = (char*)d_ws;
  // persistent regions
  u16* xt = (u16*)(ws + 0);                       // 16,777,216
  u16* A = (u16*)(ws + 16777216);                 // 67,108,864 (ends 83,886,080)
  u32* meta_hh = (u32*)(ws + 83886080);           // 4,718,592 (incl. pad + over-read slack)
  u32* meta_ih = (u32*)(ws + 88604672);           // 1,179,648
  float* stats = (float*)(ws + 89784320);         // 1,048,576
  float* rowvg = (float*)(ws + 90832896);         // 16,384
  float* rowvb = (float*)(ws + 90849280);         // 16,384
  int* rp_hh = (int*)(ws + 90865664);             // 131,080 (32769 ints)
  int* rp_ih = (int*)(ws + 90996744);             // 32,772  (8193 ints) end 91,029,516

  // preprocessing scratch aliased into upper half of A (dead before first step)
  char* scr = ws + 50331648;
  int* hist_hh2 = (int*)(scr + 0);                // 8,388,608
  int* cur_hh2 = (int*)(scr + 8388608);           // 8,388,608
  int* hist_ih2 = (int*)(scr + 16777216);         // 2,097,152
  int* cur_ih2 = (int*)(scr + 18874368);          // 2,097,152
  float* rvg_rep = (float*)(scr + 20971520);      // 1,048,576
  float* rvb_rep = (float*)(scr + 22020096);      // 1,048,576
  int* rowtot_hh2 = (int*)(scr + 23068672);       // 131,072
  int* rowtot_ih2 = (int*)(scr + 23199744);       // 32,768  (scratch end +23,232,512)

  hipMemsetAsync(scr, 0, 23232512, stream);                   // hist2 + cur2 + reps + rowtots
  hipMemsetAsync(ws + 83886080, 0, 6946816, stream);          // meta_hh + meta_ih + stats

  k_hist2<<<N_HH / 256, 256, 0, stream>>>(hh_rows, hh_cols, N_HH, hist_hh2);
  k_hist2<<<N_IH / 256, 256, 0, stream>>>(ih_rows, ih_cols, N_IH, hist_ih2);
  k_rowtot2<<<NB_HH / 4, 256, 0, stream>>>(hist_hh2, rowtot_hh2);
  k_rowtot2<<<NB_IH / 4, 256, 0, stream>>>(hist_ih2, rowtot_ih2);
  k_scan3<<<1, 256, 0, stream>>>(rowtot_hh2, rp_hh, NB_HH / 256);
  k_scan3<<<1, 256, 0, stream>>>(rowtot_ih2, rp_ih, NB_IH / 256);
  k_repbase2<<<NB_HH / 4, 256, 0, stream>>>(hist_hh2, rp_hh, cur_hh2);
  k_repbase2<<<NB_IH / 4, 256, 0, stream>>>(hist_ih2, rp_ih, cur_ih2);
  k_scatter2<<<N_HH / 256, 256, 0, stream>>>(hh_rows, hh_cols, hh_vals, N_HH, cur_hh2, meta_hh,
                                             gamma, beta, rvg_rep, rvb_rep, 1);
  k_scatter2<<<N_IH / 256, 256, 0, stream>>>(ih_rows, ih_cols, ih_vals, N_IH, cur_ih2, meta_ih,
                                             gamma, beta, rvg_rep, rvb_rep, 0);
  k_rvred<<<HD / 4, 256, 0, stream>>>(rvg_rep, rvb_rep, rowvg, rowvb);
  k_xt<<<TT * (II / 64), 256, 0, stream>>>(x, xt);

  for (int t = 0; t < TT; ++t) {
    const u16* xt_t = xt + (size_t)t * II * BB;
    const u16* Aprev = (t == 0) ? A : A + (size_t)(t - 1) * HD * BB;
    u16* Acur = A + (size_t)t * HD * BB;
    const float* st_prev = (t == 0) ? stats : stats + (size_t)(t - 1) * (2 * NREP * 64);
    float* st_cur = stats + (size_t)t * (2 * NREP * 64);
    k_step2<<<256, 256, 0, stream>>>(meta_hh, rp_hh, meta_ih, rp_ih, xt_t, Aprev, Acur,
                                     st_prev, st_cur, b_ih, b_hh, rowvg, rowvb,
                                     (t == 0) ? 1 : 0);
  }

  k_out<<<TT * (HD / 64), 256, 0, stream>>>(A, stats, gamma, beta, (float*)d_out);
}

// Round 7
// 3457.589 us; speedup vs baseline: 1.2319x; 1.2319x over previous
//
#include <hip/hip_runtime.h>
#include <cstdint>

#define TT 128
#define BB 64
#define II 1024
#define HD 4096
#define N_IH 262144
#define N_HH 1048576
#define LN_EPS 1e-5f

typedef unsigned int u32;
typedef unsigned short u16;
using bf16x8 = __attribute__((ext_vector_type(8))) short;   // raw 16B fragment
using f32x4 = __attribute__((ext_vector_type(4))) float;
using f32x2v = __attribute__((ext_vector_type(2))) float;

__device__ __forceinline__ u32 f2bf_bits(float f) {
  u32 u = __float_as_uint(f);
  return (u + 0x7FFFu + ((u >> 16) & 1u)) >> 16;   // RTNE, finite inputs
}
__device__ __forceinline__ float bf2f(u16 h) { return __uint_as_float(((u32)h) << 16); }

// MFMA via inline asm: avoids builtin signature (v8bf16 vs v8i16) portability
// issue; gfx950 unified VGPR/AGPR file allows v[] operands (cdna4_isa §10).
__device__ __forceinline__ void mfma16(f32x4& c, bf16x8 a, bf16x8 b) {
  asm("v_mfma_f32_16x16x32_bf16 %0, %1, %2, %0" : "+v"(c) : "v"(a), "v"(b));
}

// ---------------- preprocessing: densify + fold + swizzle ----------------
// W_hh in 4 row-quarter passes through a 16MB f32 scratch:
//   memset -> k_dens_hh(q): atomicAdd duplicates (matches segment_sum)
//          -> k_fold_hh(q): gamma-fold, bf16, MFMA-fragment swizzle, rowvg/rowvb.
// Swizzled layout: per (row-tile rt, k-step ks) a 512-elem block; element
// (r,k) at ((r&15) + 16*((k&31)>>3))*8 + (k&7) -> wave A-frag load is exactly
// lane*16B (row = lane&15, k = (lane>>4)*8 + j).

__global__ void k_dens_hh(const int* __restrict__ rows, const int* __restrict__ cols,
                          const float* __restrict__ vals, float* __restrict__ W32, int q) {
  int e = blockIdx.x * 256 + threadIdx.x;
  if (e >= N_HH) return;
  int r = rows[e];
  if ((r >> 10) != q) return;
  atomicAdd(&W32[(size_t)(r & 1023) * HD + cols[e]], vals[e]);
}

__global__ void k_dens_ih(const int* __restrict__ rows, const int* __restrict__ cols,
                          const float* __restrict__ vals, float* __restrict__ W32) {
  int e = blockIdx.x * 256 + threadIdx.x;
  if (e >= N_IH) return;
  atomicAdd(&W32[(size_t)rows[e] * II + cols[e]], vals[e]);
}

__global__ __launch_bounds__(256) void k_fold_hh(const float* __restrict__ W32,
    const float* __restrict__ gamma, const float* __restrict__ beta,
    u16* __restrict__ Whh, float* __restrict__ rowvg, float* __restrict__ rowvb, int q) {
  int w = threadIdx.x >> 6, lane = threadIdx.x & 63;
  int rl = blockIdx.x * 4 + w;        // 0..1023 within quarter
  int row = q * 1024 + rl;
  const float* src = W32 + (size_t)rl * HD;
  size_t rtbase = (size_t)(row >> 4) * 128 * 512;
  int lrow8 = (row & 15) * 8;
  float rvg = 0.f, rvb = 0.f;
#pragma unroll
  for (int jj = 0; jj < 8; ++jj) {
    int o = lane + jj * 64;           // octet index 0..511 (k0 = o*8)
    int k0 = o * 8;
    float4 v0 = *(const float4*)(src + k0);
    float4 v1 = *(const float4*)(src + k0 + 4);
    float4 g0 = *(const float4*)(gamma + k0);
    float4 g1 = *(const float4*)(gamma + k0 + 4);
    float4 t0 = *(const float4*)(beta + k0);
    float4 t1 = *(const float4*)(beta + k0 + 4);
    float a0 = v0.x * g0.x, a1 = v0.y * g0.y, a2 = v0.z * g0.z, a3 = v0.w * g0.w;
    float a4 = v1.x * g1.x, a5 = v1.y * g1.y, a6 = v1.z * g1.z, a7 = v1.w * g1.w;
    rvg += (a0 + a1) + (a2 + a3) + (a4 + a5) + (a6 + a7);
    rvb += (v0.x * t0.x + v0.y * t0.y) + (v0.z * t0.z + v0.w * t0.w)
         + (v1.x * t1.x + v1.y * t1.y) + (v1.z * t1.z + v1.w * t1.w);
    uint4 pk;
    pk.x = f2bf_bits(a0) | (f2bf_bits(a1) << 16);
    pk.y = f2bf_bits(a2) | (f2bf_bits(a3) << 16);
    pk.z = f2bf_bits(a4) | (f2bf_bits(a5) << 16);
    pk.w = f2bf_bits(a6) | (f2bf_bits(a7) << 16);
    size_t dst = rtbase + (size_t)(o >> 2) * 512 + (size_t)(lrow8 + 128 * (o & 3));
    *(uint4*)(Whh + dst) = pk;
  }
#pragma unroll
  for (int d = 1; d < 64; d <<= 1) { rvg += __shfl_xor(rvg, d); rvb += __shfl_xor(rvb, d); }
  if (lane == 0) { rowvg[row] = rvg; rowvb[row] = rvb; }
}

__global__ __launch_bounds__(256) void k_fold_ih(const float* __restrict__ W32,
                                                 u16* __restrict__ Wih) {
  int w = threadIdx.x >> 6, lane = threadIdx.x & 63;
  int row = blockIdx.x * 4 + w;       // 0..4095
  const float* src = W32 + (size_t)row * II;
  size_t rtbase = (size_t)(row >> 4) * 32 * 512;
  int lrow8 = (row & 15) * 8;
#pragma unroll
  for (int jj = 0; jj < 2; ++jj) {
    int o = lane + jj * 64;           // octet 0..127
    int k0 = o * 8;
    float4 v0 = *(const float4*)(src + k0);
    float4 v1 = *(const float4*)(src + k0 + 4);
    uint4 pk;
    pk.x = f2bf_bits(v0.x) | (f2bf_bits(v0.y) << 16);
    pk.y = f2bf_bits(v0.z) | (f2bf_bits(v0.w) << 16);
    pk.z = f2bf_bits(v1.x) | (f2bf_bits(v1.y) << 16);
    pk.w = f2bf_bits(v1.z) | (f2bf_bits(v1.w) << 16);
    size_t dst = rtbase + (size_t)(o >> 2) * 512 + (size_t)(lrow8 + 128 * (o & 3));
    *(uint4*)(Wih + dst) = pk;
  }
}

// x (B,T,I) f32 -> xt [t][b][i] bf16 (batch-major: GEMM B-operand layout)
__global__ __launch_bounds__(256) void k_xt(const float* __restrict__ x, u16* __restrict__ xt) {
  int t = blockIdx.x >> 6, b = blockIdx.x & 63;
  int i = threadIdx.x * 4;
  float4 v = *(const float4*)(x + ((size_t)b * TT + t) * II + i);
  uint2 pk;
  pk.x = f2bf_bits(v.x) | (f2bf_bits(v.y) << 16);
  pk.y = f2bf_bits(v.z) | (f2bf_bits(v.w) << 16);
  *(uint2*)(xt + ((size_t)t * BB + b) * II + i) = pk;
}

// ---------------- per-step dense GEMM kernel ----------------
// grid 256 (block = 16 rows), 512 thr (8 waves). Waves split K (HH: 512 cols
// each, IH: 128 each). Per K-step: 1 swizzled W-frag load + 4 B-frag loads +
// 4 independent MFMAs, no barriers in the K-loop. Cross-wave K-reduce via
// LDS; fused epilogue: LN-folded HH + tanh + stats + out[t-1] write.
__global__ __launch_bounds__(512, 1) void k_gemm(
    const u16* __restrict__ Whh, const u16* __restrict__ Wih,
    const u16* __restrict__ xt_t, const u16* __restrict__ Aprev,
    u16* __restrict__ Acur,
    const float* __restrict__ st_prev, float* __restrict__ st_cur,
    const float* __restrict__ b_ih, const float* __restrict__ b_hh,
    const float* __restrict__ rowvg, const float* __restrict__ rowvb,
    const float* __restrict__ gamma, const float* __restrict__ beta,
    float* __restrict__ out, int t) {
  __shared__ float epil[8][2][16][65];
  __shared__ float s_mu[64], s_rs[64], s_sum[64], s_sq[64];
  int tid = threadIdx.x, w = tid >> 6, lane = tid & 63;
  int rt = blockIdx.x, r0 = rt << 4;
  int first = (t == 0);

  if (tid < 64) { s_sum[tid] = 0.f; s_sq[tid] = 0.f; }
  if (w == 7 && !first) {
    float s = 0.f, q = 0.f;
#pragma unroll
    for (int r2 = 0; r2 < 16; ++r2) {
      s += st_prev[r2 * 64 + lane];
      q += st_prev[1024 + r2 * 64 + lane];
    }
    float mu = s * (1.0f / HD);
    float var = q * (1.0f / HD) - mu * mu;
    s_mu[lane] = mu;
    s_rs[lane] = rsqrtf(var + LN_EPS);
  }

  int bb0 = lane & 15;
  int koff = (lane >> 4) * 8;
  f32x4 z4 = {0.f, 0.f, 0.f, 0.f};
  f32x4 aH[4] = {z4, z4, z4, z4};
  f32x4 aI[4] = {z4, z4, z4, z4};

  {  // IH: K=1024, wave w owns k-steps [w*4, w*4+4)
    const bf16x8* wp = (const bf16x8*)Wih + (size_t)rt * 2048 + lane;
#pragma unroll
    for (int i = 0; i < 4; ++i) {
      int ks = w * 4 + i;
      bf16x8 af = wp[ks * 64];
      const u16* cp = xt_t + ks * 32 + koff;
#pragma unroll
      for (int ct = 0; ct < 4; ++ct) {
        bf16x8 bf = *(const bf16x8*)(cp + (size_t)(bb0 + ct * 16) * II);
        mfma16(aI[ct], af, bf);
      }
    }
  }
  if (!first) {  // HH: K=4096, wave w owns k-steps [w*16, w*16+16)
    const bf16x8* wp = (const bf16x8*)Whh + (size_t)rt * 8192 + lane;
#pragma unroll 4
    for (int i = 0; i < 16; ++i) {
      int ks = w * 16 + i;
      bf16x8 af = wp[ks * 64];
      const u16* cp = Aprev + ks * 32 + koff;
#pragma unroll
      for (int ct = 0; ct < 4; ++ct) {
        bf16x8 bf = *(const bf16x8*)(cp + (size_t)(bb0 + ct * 16) * HD);
        mfma16(aH[ct], af, bf);
      }
    }
  }

  // MFMA-dst -> read hazard fence (inline-asm MFMA bypasses the compiler's
  // hazard recognizer): 24 cycles of s_nop, data-tied to all accumulators so
  // the LDS writes below cannot be scheduled before it.
  asm volatile("s_nop 7\n\ts_nop 7\n\ts_nop 7"
               : "+v"(aH[0]), "+v"(aH[1]), "+v"(aH[2]), "+v"(aH[3]),
                 "+v"(aI[0]), "+v"(aI[1]), "+v"(aI[2]), "+v"(aI[3]));

  {  // partials -> LDS  (C/D layout: col=lane&15, row=(lane>>4)*4+reg)
    int rr = lane >> 4;
#pragma unroll
    for (int ct = 0; ct < 4; ++ct)
#pragma unroll
      for (int j = 0; j < 4; ++j) {
        epil[w][0][rr * 4 + j][ct * 16 + bb0] = aH[ct][j];
        epil[w][1][rr * 4 + j][ct * 16 + bb0] = aI[ct][j];
      }
  }
  __syncthreads();

  int b = tid >> 3, rp2 = (tid & 7) * 2;
  int r = r0 + rp2;

  if (!first) {  // out[t-1] for this block's rows (stats[t-1] now in s_mu/s_rs)
    u32 a2 = *(const u32*)(Aprev + (size_t)b * HD + r);
    float mu = s_mu[b], rs = s_rs[b];
    float hn0 = (bf2f((u16)(a2 & 0xFFFFu)) - mu) * rs * gamma[r] + beta[r];
    float hn1 = (bf2f((u16)(a2 >> 16)) - mu) * rs * gamma[r + 1] + beta[r + 1];
    f32x2v o2 = {hn0, hn1};
    *(f32x2v*)(out + ((size_t)b * TT + (t - 1)) * HD + r) = o2;
  }

  float sh0 = 0.f, sh1 = 0.f, si0 = 0.f, si1 = 0.f;
#pragma unroll
  for (int ww = 0; ww < 8; ++ww) {
    sh0 += epil[ww][0][rp2][b];     sh1 += epil[ww][0][rp2 + 1][b];
    si0 += epil[ww][1][rp2][b];     si1 += epil[ww][1][rp2 + 1][b];
  }
  float bs0 = b_ih[r] + b_hh[r];
  float bs1 = b_ih[r + 1] + b_hh[r + 1];
  float pre0, pre1;
  if (first) {
    pre0 = si0 + bs0;
    pre1 = si1 + bs1;
  } else {
    float mu = s_mu[b], rs = s_rs[b];
    pre0 = si0 + bs0 + rowvb[r] + rs * (sh0 - mu * rowvg[r]);
    pre1 = si1 + bs1 + rowvb[r + 1] + rs * (sh1 - mu * rowvg[r + 1]);
  }
  float h0 = 1.0f - 2.0f / (__expf(2.0f * pre0) + 1.0f);   // tanh
  float h1 = 1.0f - 2.0f / (__expf(2.0f * pre1) + 1.0f);
  *(u32*)(Acur + (size_t)b * HD + r) = f2bf_bits(h0) | (f2bf_bits(h1) << 16);
  atomicAdd(&s_sum[b], h0 + h1);
  atomicAdd(&s_sq[b], h0 * h0 + h1 * h1);
  __syncthreads();
  if (tid < 64) {
    int rep = rt & 15;
    atomicAdd(&st_cur[rep * 64 + tid], s_sum[tid]);
    atomicAdd(&st_cur[1024 + rep * 64 + tid], s_sq[tid]);
  }
}

// ---------------- final slice: out[:,127,:] + h_last ----------------
__global__ __launch_bounds__(256) void k_fin(const u16* __restrict__ Alast,
    const float* __restrict__ st, const float* __restrict__ gamma,
    const float* __restrict__ beta, float* __restrict__ out) {
  __shared__ float s_mu1, s_rs1;
  int b = blockIdx.x, tid = threadIdx.x;
  if (tid == 0) {
    float s = 0.f, q = 0.f;
    for (int r2 = 0; r2 < 16; ++r2) {
      s += st[r2 * 64 + b];
      q += st[1024 + r2 * 64 + b];
    }
    float mu = s * (1.0f / HD);
    float var = q * (1.0f / HD) - mu * mu;
    s_mu1 = mu;
    s_rs1 = rsqrtf(var + LN_EPS);
  }
  __syncthreads();
  float mu = s_mu1, rs = s_rs1;
#pragma unroll
  for (int i = 0; i < 16; ++i) {
    int r = i * 256 + tid;
    float a = bf2f(Alast[(size_t)b * HD + r]);
    float hn = (a - mu) * rs * gamma[r] + beta[r];
    out[((size_t)b * TT + (TT - 1)) * HD + r] = hn;
    out[(size_t)BB * TT * HD + (size_t)b * HD + r] = hn;
  }
}

// ---------------- host launch ----------------

extern "C" void kernel_launch(void* const* d_in, const int* in_sizes, int n_in,
                              void* d_out, int out_size, void* d_ws, size_t ws_size,
                              hipStream_t stream) {
  const float* x = (const float*)d_in[0];
  const int* ih_rows = (const int*)d_in[1];
  const int* ih_cols = (const int*)d_in[2];
  const float* ih_vals = (const float*)d_in[3];
  const int* hh_rows = (const int*)d_in[4];
  const int* hh_cols = (const int*)d_in[5];
  const float* hh_vals = (const float*)d_in[6];
  const float* b_ih = (const float*)d_in[7];
  const float* b_hh = (const float*)d_in[8];
  const float* gamma = (const float*)d_in[9];
  const float* beta = (const float*)d_in[10];

  char* ws = (char*)d_ws;
  u16* xt = (u16*)(ws);                        // 16,777,216  [t][b][i] bf16
  u16* Whh = (u16*)(ws + 16777216);            // 33,554,432  swizzled bf16 (gamma-folded)
  u16* Wih = (u16*)(ws + 50331648);            //  8,388,608  swizzled bf16
  u16* A2 = (u16*)(ws + 58720256);             //  1,048,576  ping-pong [2][64][4096] bf16
  float* stats = (float*)(ws + 59768832);      //  1,048,576  [128][2][16][64]
  float* rowvg = (float*)(ws + 60817408);      //     16,384
  float* rowvb = (float*)(ws + 60833792);      //     16,384
  float* W32 = (float*)(ws + 60850176);        // 16,777,216  f32 densify scratch (peak ~74MB)

  hipMemsetAsync(stats, 0, 1048576, stream);
  hipMemsetAsync(A2, 0, 1048576, stream);

  for (int q = 0; q < 4; ++q) {                // HH in 4 row-quarter passes
    hipMemsetAsync(W32, 0, 16777216, stream);
    k_dens_hh<<<N_HH / 256, 256, 0, stream>>>(hh_rows, hh_cols, hh_vals, W32, q);
    k_fold_hh<<<256, 256, 0, stream>>>(W32, gamma, beta, Whh, rowvg, rowvb, q);
  }
  hipMemsetAsync(W32, 0, 16777216, stream);
  k_dens_ih<<<N_IH / 256, 256, 0, stream>>>(ih_rows, ih_cols, ih_vals, W32);
  k_fold_ih<<<1024, 256, 0, stream>>>(W32, Wih);
  k_xt<<<TT * BB, 256, 0, stream>>>(x, xt);

  for (int t = 0; t < TT; ++t) {
    const u16* xt_t = xt + (size_t)t * (BB * II);
    const u16* Aprev = A2 + (size_t)((t + 1) & 1) * (BB * HD);
    u16* Acur = A2 + (size_t)(t & 1) * (BB * HD);
    const float* st_prev = stats + (size_t)((t > 0) ? (t - 1) : 0) * 2048;
    float* st_cur = stats + (size_t)t * 2048;
    k_gemm<<<256, 512, 0, stream>>>(Whh, Wih, xt_t, Aprev, Acur, st_prev, st_cur,
                                    b_ih, b_hh, rowvg, rowvb, gamma, beta,
                                    (float*)d_out, t);
  }

  k_fin<<<BB, 256, 0, stream>>>(A2 + (size_t)((TT - 1) & 1) * (BB * HD),
                                stats + (size_t)(TT - 1) * 2048, gamma, beta,
                                (float*)d_out);
}

// Round 8
// 2057.423 us; speedup vs baseline: 2.0703x; 1.6805x over previous
//
#include <hip/hip_runtime.h>
#include <cstdint>

#define TT 128
#define BB 64
#define II 1024
#define HD 4096
#define N_IH 262144
#define N_HH 1048576
#define LN_EPS 1e-5f

typedef unsigned int u32;
typedef unsigned short u16;
using bf16x8 = __attribute__((ext_vector_type(8))) short;   // raw 16B fragment
using f32x4 = __attribute__((ext_vector_type(4))) float;
using f32x2v = __attribute__((ext_vector_type(2))) float;

__device__ __forceinline__ u32 f2bf_bits(float f) {
  u32 u = __float_as_uint(f);
  return (u + 0x7FFFu + ((u >> 16) & 1u)) >> 16;   // RTNE, finite inputs
}
__device__ __forceinline__ float bf2f(u16 h) { return __uint_as_float(((u32)h) << 16); }

// MFMA via inline asm (verified working in R7 on gfx950 unified VGPR file).
__device__ __forceinline__ void mfma16(f32x4& c, bf16x8 a, bf16x8 b) {
  asm("v_mfma_f32_16x16x32_bf16 %0, %1, %2, %0" : "+v"(c) : "v"(a), "v"(b));
}

// B-operand fragment-swizzled activation layout: element (k, b) lives at
// ((k>>5)*4 + (b>>4))*512 + ((b&15) + 16*((k&31)>>3))*8 + (k&7)
// -> a wave's B-frag load for (ks, ct) is base + (ks*4+ct)*512 + lane*8:
//    one fully-coalesced 1KB load (same shape as the swizzled W loads).
__device__ __forceinline__ int aoff(int k, int b) {
  return (((k >> 5) * 4 + (b >> 4)) << 9) + (((b & 15) + 16 * ((k & 31) >> 3)) << 3) + (k & 7);
}

// ---------------- preprocessing: densify + fold + swizzle ----------------

__global__ void k_dens_hh(const int* __restrict__ rows, const int* __restrict__ cols,
                          const float* __restrict__ vals, float* __restrict__ W32, int q) {
  int e = blockIdx.x * 256 + threadIdx.x;
  if (e >= N_HH) return;
  int r = rows[e];
  if ((r >> 10) != q) return;
  atomicAdd(&W32[(size_t)(r & 1023) * HD + cols[e]], vals[e]);
}

__global__ void k_dens_ih(const int* __restrict__ rows, const int* __restrict__ cols,
                          const float* __restrict__ vals, float* __restrict__ W32) {
  int e = blockIdx.x * 256 + threadIdx.x;
  if (e >= N_IH) return;
  atomicAdd(&W32[(size_t)rows[e] * II + cols[e]], vals[e]);
}

__global__ __launch_bounds__(256) void k_fold_hh(const float* __restrict__ W32,
    const float* __restrict__ gamma, const float* __restrict__ beta,
    u16* __restrict__ Whh, float* __restrict__ rowvg, float* __restrict__ rowvb, int q) {
  int w = threadIdx.x >> 6, lane = threadIdx.x & 63;
  int rl = blockIdx.x * 4 + w;        // 0..1023 within quarter
  int row = q * 1024 + rl;
  const float* src = W32 + (size_t)rl * HD;
  size_t rtbase = (size_t)(row >> 4) * 128 * 512;
  int lrow8 = (row & 15) * 8;
  float rvg = 0.f, rvb = 0.f;
#pragma unroll
  for (int jj = 0; jj < 8; ++jj) {
    int o = lane + jj * 64;           // octet index 0..511 (k0 = o*8)
    int k0 = o * 8;
    float4 v0 = *(const float4*)(src + k0);
    float4 v1 = *(const float4*)(src + k0 + 4);
    float4 g0 = *(const float4*)(gamma + k0);
    float4 g1 = *(const float4*)(gamma + k0 + 4);
    float4 t0 = *(const float4*)(beta + k0);
    float4 t1 = *(const float4*)(beta + k0 + 4);
    float a0 = v0.x * g0.x, a1 = v0.y * g0.y, a2 = v0.z * g0.z, a3 = v0.w * g0.w;
    float a4 = v1.x * g1.x, a5 = v1.y * g1.y, a6 = v1.z * g1.z, a7 = v1.w * g1.w;
    rvg += (a0 + a1) + (a2 + a3) + (a4 + a5) + (a6 + a7);
    rvb += (v0.x * t0.x + v0.y * t0.y) + (v0.z * t0.z + v0.w * t0.w)
         + (v1.x * t1.x + v1.y * t1.y) + (v1.z * t1.z + v1.w * t1.w);
    uint4 pk;
    pk.x = f2bf_bits(a0) | (f2bf_bits(a1) << 16);
    pk.y = f2bf_bits(a2) | (f2bf_bits(a3) << 16);
    pk.z = f2bf_bits(a4) | (f2bf_bits(a5) << 16);
    pk.w = f2bf_bits(a6) | (f2bf_bits(a7) << 16);
    size_t dst = rtbase + (size_t)(o >> 2) * 512 + (size_t)(lrow8 + 128 * (o & 3));
    *(uint4*)(Whh + dst) = pk;
  }
#pragma unroll
  for (int d = 1; d < 64; d <<= 1) { rvg += __shfl_xor(rvg, d); rvb += __shfl_xor(rvb, d); }
  if (lane == 0) { rowvg[row] = rvg; rowvb[row] = rvb; }
}

__global__ __launch_bounds__(256) void k_fold_ih(const float* __restrict__ W32,
                                                 u16* __restrict__ Wih) {
  int w = threadIdx.x >> 6, lane = threadIdx.x & 63;
  int row = blockIdx.x * 4 + w;       // 0..4095
  const float* src = W32 + (size_t)row * II;
  size_t rtbase = (size_t)(row >> 4) * 32 * 512;
  int lrow8 = (row & 15) * 8;
#pragma unroll
  for (int jj = 0; jj < 2; ++jj) {
    int o = lane + jj * 64;           // octet 0..127
    int k0 = o * 8;
    float4 v0 = *(const float4*)(src + k0);
    float4 v1 = *(const float4*)(src + k0 + 4);
    uint4 pk;
    pk.x = f2bf_bits(v0.x) | (f2bf_bits(v0.y) << 16);
    pk.y = f2bf_bits(v0.z) | (f2bf_bits(v0.w) << 16);
    pk.z = f2bf_bits(v1.x) | (f2bf_bits(v1.y) << 16);
    pk.w = f2bf_bits(v1.z) | (f2bf_bits(v1.w) << 16);
    size_t dst = rtbase + (size_t)(o >> 2) * 512 + (size_t)(lrow8 + 128 * (o & 3));
    *(uint4*)(Wih + dst) = pk;
  }
}

// x (B,T,I) f32 -> xt [t]{B-frag swizzled 64x1024} bf16
__global__ __launch_bounds__(256) void k_xt(const float* __restrict__ x, u16* __restrict__ xt) {
  int t = blockIdx.x >> 6, b = blockIdx.x & 63;
  int i = threadIdx.x * 4;
  float4 v = *(const float4*)(x + ((size_t)b * TT + t) * II + i);
  uint2 pk;
  pk.x = f2bf_bits(v.x) | (f2bf_bits(v.y) << 16);
  pk.y = f2bf_bits(v.z) | (f2bf_bits(v.w) << 16);
  *(uint2*)(xt + (size_t)t * (BB * II) + aoff(i, b)) = pk;   // i%8 in {0,4}: 8B-aligned
}

// ---------------- per-step dense GEMM kernel ----------------
// grid 256 (block = 16 rows), 512 thr (8 waves). Waves split K (HH: 512 cols
// each, IH: 128 each). All K-loop loads are coalesced 1KB fragment streams
// (W and activations both fragment-swizzled). No barriers in the K-loop.
// Cross-wave K-reduce via LDS; fused epilogue: LN-folded HH + tanh + stats +
// out[t-1] write.
__global__ __launch_bounds__(512, 1) void k_gemm(
    const u16* __restrict__ Whh, const u16* __restrict__ Wih,
    const u16* __restrict__ xt_t, const u16* __restrict__ Aprev,
    u16* __restrict__ Acur,
    const float* __restrict__ st_prev, float* __restrict__ st_cur,
    const float* __restrict__ b_ih, const float* __restrict__ b_hh,
    const float* __restrict__ rowvg, const float* __restrict__ rowvb,
    const float* __restrict__ gamma, const float* __restrict__ beta,
    float* __restrict__ out, int t) {
  __shared__ float epil[8][2][16][65];
  __shared__ float s_mu[64], s_rs[64], s_sum[64], s_sq[64];
  int tid = threadIdx.x, w = tid >> 6, lane = tid & 63;
  int rt = blockIdx.x, r0 = rt << 4;
  int first = (t == 0);

  if (tid < 64) { s_sum[tid] = 0.f; s_sq[tid] = 0.f; }
  if (w == 7 && !first) {
    float s = 0.f, q = 0.f;
#pragma unroll
    for (int r2 = 0; r2 < 16; ++r2) {
      s += st_prev[r2 * 64 + lane];
      q += st_prev[1024 + r2 * 64 + lane];
    }
    float mu = s * (1.0f / HD);
    float var = q * (1.0f / HD) - mu * mu;
    s_mu[lane] = mu;
    s_rs[lane] = rsqrtf(var + LN_EPS);
  }

  int bb0 = lane & 15;
  f32x4 z4 = {0.f, 0.f, 0.f, 0.f};
  f32x4 aH[4] = {z4, z4, z4, z4};
  f32x4 aI[4] = {z4, z4, z4, z4};

  {  // IH: K=1024, wave w owns k-steps [w*4, w*4+4)
    const bf16x8* wp = (const bf16x8*)Wih + (size_t)rt * 2048 + lane;
    const bf16x8* bp = (const bf16x8*)xt_t + lane;
#pragma unroll
    for (int i = 0; i < 4; ++i) {
      int ks = w * 4 + i;
      bf16x8 af = wp[ks * 64];
#pragma unroll
      for (int ct = 0; ct < 4; ++ct) {
        bf16x8 bf = bp[(ks * 4 + ct) * 64];
        mfma16(aI[ct], af, bf);
      }
    }
  }
  if (!first) {  // HH: K=4096, wave w owns k-steps [w*16, w*16+16)
    const bf16x8* wp = (const bf16x8*)Whh + (size_t)rt * 8192 + lane;
    const bf16x8* bp = (const bf16x8*)Aprev + lane;
#pragma unroll 4
    for (int i = 0; i < 16; ++i) {
      int ks = w * 16 + i;
      bf16x8 af = wp[ks * 64];
#pragma unroll
      for (int ct = 0; ct < 4; ++ct) {
        bf16x8 bf = bp[(ks * 4 + ct) * 64];
        mfma16(aH[ct], af, bf);
      }
    }
  }

  // MFMA-dst -> read hazard fence (inline-asm MFMA bypasses the compiler's
  // hazard recognizer): 24 cycles of s_nop, data-tied to all accumulators.
  asm volatile("s_nop 7\n\ts_nop 7\n\ts_nop 7"
               : "+v"(aH[0]), "+v"(aH[1]), "+v"(aH[2]), "+v"(aH[3]),
                 "+v"(aI[0]), "+v"(aI[1]), "+v"(aI[2]), "+v"(aI[3]));

  {  // partials -> LDS  (C/D layout: col=lane&15, row=(lane>>4)*4+reg)
    int rr = lane >> 4;
#pragma unroll
    for (int ct = 0; ct < 4; ++ct)
#pragma unroll
      for (int j = 0; j < 4; ++j) {
        epil[w][0][rr * 4 + j][ct * 16 + bb0] = aH[ct][j];
        epil[w][1][rr * 4 + j][ct * 16 + bb0] = aI[ct][j];
      }
  }
  __syncthreads();

  int b = tid >> 3, rp2 = (tid & 7) * 2;
  int r = r0 + rp2;

  if (!first) {  // out[t-1] for this block's rows (stats[t-1] now in s_mu/s_rs)
    u32 a2 = *(const u32*)(Aprev + aoff(r, b));
    float mu = s_mu[b], rs = s_rs[b];
    float hn0 = (bf2f((u16)(a2 & 0xFFFFu)) - mu) * rs * gamma[r] + beta[r];
    float hn1 = (bf2f((u16)(a2 >> 16)) - mu) * rs * gamma[r + 1] + beta[r + 1];
    f32x2v o2 = {hn0, hn1};
    *(f32x2v*)(out + ((size_t)b * TT + (t - 1)) * HD + r) = o2;
  }

  float sh0 = 0.f, sh1 = 0.f, si0 = 0.f, si1 = 0.f;
#pragma unroll
  for (int ww = 0; ww < 8; ++ww) {
    sh0 += epil[ww][0][rp2][b];     sh1 += epil[ww][0][rp2 + 1][b];
    si0 += epil[ww][1][rp2][b];     si1 += epil[ww][1][rp2 + 1][b];
  }
  float bs0 = b_ih[r] + b_hh[r];
  float bs1 = b_ih[r + 1] + b_hh[r + 1];
  float pre0, pre1;
  if (first) {
    pre0 = si0 + bs0;
    pre1 = si1 + bs1;
  } else {
    float mu = s_mu[b], rs = s_rs[b];
    pre0 = si0 + bs0 + rowvb[r] + rs * (sh0 - mu * rowvg[r]);
    pre1 = si1 + bs1 + rowvb[r + 1] + rs * (sh1 - mu * rowvg[r + 1]);
  }
  float h0 = 1.0f - 2.0f / (__expf(2.0f * pre0) + 1.0f);   // tanh
  float h1 = 1.0f - 2.0f / (__expf(2.0f * pre1) + 1.0f);
  *(u32*)(Acur + aoff(r, b)) = f2bf_bits(h0) | (f2bf_bits(h1) << 16);   // r%8 even: aligned
  atomicAdd(&s_sum[b], h0 + h1);
  atomicAdd(&s_sq[b], h0 * h0 + h1 * h1);
  __syncthreads();
  if (tid < 64) {
    int rep = rt & 15;
    atomicAdd(&st_cur[rep * 64 + tid], s_sum[tid]);
    atomicAdd(&st_cur[1024 + rep * 64 + tid], s_sq[tid]);
  }
}

// ---------------- final slice: out[:,127,:] + h_last ----------------
__global__ __launch_bounds__(256) void k_fin(const u16* __restrict__ Alast,
    const float* __restrict__ st, const float* __restrict__ gamma,
    const float* __restrict__ beta, float* __restrict__ out) {
  __shared__ float s_mu1, s_rs1;
  int b = blockIdx.x, tid = threadIdx.x;
  if (tid == 0) {
    float s = 0.f, q = 0.f;
    for (int r2 = 0; r2 < 16; ++r2) {
      s += st[r2 * 64 + b];
      q += st[1024 + r2 * 64 + b];
    }
    float mu = s * (1.0f / HD);
    float var = q * (1.0f / HD) - mu * mu;
    s_mu1 = mu;
    s_rs1 = rsqrtf(var + LN_EPS);
  }
  __syncthreads();
  float mu = s_mu1, rs = s_rs1;
#pragma unroll
  for (int i = 0; i < 16; ++i) {
    int r = i * 256 + tid;
    float a = bf2f(Alast[aoff(r, b)]);
    float hn = (a - mu) * rs * gamma[r] + beta[r];
    out[((size_t)b * TT + (TT - 1)) * HD + r] = hn;
    out[(size_t)BB * TT * HD + (size_t)b * HD + r] = hn;
  }
}

// ---------------- host launch ----------------

extern "C" void kernel_launch(void* const* d_in, const int* in_sizes, int n_in,
                              void* d_out, int out_size, void* d_ws, size_t ws_size,
                              hipStream_t stream) {
  const float* x = (const float*)d_in[0];
  const int* ih_rows = (const int*)d_in[1];
  const int* ih_cols = (const int*)d_in[2];
  const float* ih_vals = (const float*)d_in[3];
  const int* hh_rows = (const int*)d_in[4];
  const int* hh_cols = (const int*)d_in[5];
  const float* hh_vals = (const float*)d_in[6];
  const float* b_ih = (const float*)d_in[7];
  const float* b_hh = (const float*)d_in[8];
  const float* gamma = (const float*)d_in[9];
  const float* beta = (const float*)d_in[10];

  char* ws = (char*)d_ws;
  u16* xt = (u16*)(ws);                        // 16,777,216  [t] swizzled 64x1024 bf16
  u16* Whh = (u16*)(ws + 16777216);            // 33,554,432  swizzled bf16 (gamma-folded)
  u16* Wih = (u16*)(ws + 50331648);            //  8,388,608  swizzled bf16
  u16* A2 = (u16*)(ws + 58720256);             //  1,048,576  ping-pong, swizzled 64x4096
  float* stats = (float*)(ws + 59768832);      //  1,048,576  [128][2][16][64]
  float* rowvg = (float*)(ws + 60817408);      //     16,384
  float* rowvb = (float*)(ws + 60833792);      //     16,384
  float* W32 = (float*)(ws + 60850176);        // 16,777,216  f32 densify scratch

  hipMemsetAsync(stats, 0, 1048576, stream);
  hipMemsetAsync(A2, 0, 1048576, stream);

  for (int q = 0; q < 4; ++q) {                // HH in 4 row-quarter passes
    hipMemsetAsync(W32, 0, 16777216, stream);
    k_dens_hh<<<N_HH / 256, 256, 0, stream>>>(hh_rows, hh_cols, hh_vals, W32, q);
    k_fold_hh<<<256, 256, 0, stream>>>(W32, gamma, beta, Whh, rowvg, rowvb, q);
  }
  hipMemsetAsync(W32, 0, 16777216, stream);
  k_dens_ih<<<N_IH / 256, 256, 0, stream>>>(ih_rows, ih_cols, ih_vals, W32);
  k_fold_ih<<<1024, 256, 0, stream>>>(W32, Wih);
  k_xt<<<TT * BB, 256, 0, stream>>>(x, xt);

  for (int t = 0; t < TT; ++t) {
    const u16* xt_t = xt + (size_t)t * (BB * II);
    const u16* Aprev = A2 + (size_t)((t + 1) & 1) * (BB * HD);
    u16* Acur = A2 + (size_t)(t & 1) * (BB * HD);
    const float* st_prev = stats + (size_t)((t > 0) ? (t - 1) : 0) * 2048;
    float* st_cur = stats + (size_t)t * 2048;
    k_gemm<<<256, 512, 0, stream>>>(Whh, Wih, xt_t, Aprev, Acur, st_prev, st_cur,
                                    b_ih, b_hh, rowvg, rowvb, gamma, beta,
                                    (float*)d_out, t);
  }

  k_fin<<<BB, 256, 0, stream>>>(A2 + (size_t)((TT - 1) & 1) * (BB * HD),
                                stats + (size_t)(TT - 1) * 2048, gamma, beta,
                                (float*)d_out);
}